// Round 1
// baseline (130.835 us; speedup 1.0000x reference)
//
#include <hip/hip_runtime.h>
#include <math.h>

// Problem constants (from reference): x is [B, C, T, F] float32.
#define B_DIM 8
#define C_DIM 160
#define T_DIM 512
#define F_DIM 32
// F/4 float4s per (b,c,t) row
#define F4 (F_DIM / 4)

__device__ __forceinline__ float4 fmax4(float4 a, float4 b) {
    return make_float4(fmaxf(a.x, b.x), fmaxf(a.y, b.y),
                       fmaxf(a.z, b.z), fmaxf(a.w, b.w));
}
__device__ __forceinline__ float4 fadd4(float4 a, float4 b) {
    return make_float4(a.x + b.x, a.y + b.y, a.z + b.z, a.w + b.w);
}

// Kernel 1: M[b,t,f] = max_c x[b,c,t,f]
// One block per (b,t). 256 threads: f4 = tid&7, c-slice = tid>>5... (tid>>3), 32 slices.
__global__ __launch_bounds__(256)
void channel_max_kernel(const float* __restrict__ x, float* __restrict__ M) {
    const int bt = blockIdx.x;           // b*T + t
    const int b = bt >> 9;               // /T_DIM (512)
    const int t = bt & (T_DIM - 1);
    const int tid = threadIdx.x;
    const int f4 = tid & (F4 - 1);       // 0..7
    const int c0 = tid >> 3;             // 0..31

    const float4* __restrict__ x4 = (const float4*)x;
    float4 acc = make_float4(-INFINITY, -INFINITY, -INFINITY, -INFINITY);
    // element index (float4 units): ((b*C + c)*T + t)*F4 + f4
    #pragma unroll
    for (int c = c0; c < C_DIM; c += 32) {
        float4 v = x4[((b * C_DIM + c) * T_DIM + t) * F4 + f4];
        acc = fmax4(acc, v);
    }

    __shared__ float4 red[256];
    red[tid] = acc;
    __syncthreads();
    #pragma unroll
    for (int s = 128; s >= F4; s >>= 1) {
        if (tid < s) red[tid] = fmax4(red[tid], red[tid + s]);
        __syncthreads();
    }
    if (tid < F4) {
        ((float4*)M)[bt * F4 + tid] = red[tid];
    }
}

// Kernel 2: out[b,k,f] = max_t (x[b,k,t,f] + M[b,t,f]), k in [0, C-2]
// One block per (b,k). 256 threads: f4 = tid&7, t-slice = tid>>3 (32 slices).
__global__ __launch_bounds__(256)
void pair_out_kernel(const float* __restrict__ x, const float* __restrict__ M,
                     float* __restrict__ out) {
    const int bk = blockIdx.x;           // b*(C-1) + k
    const int b = bk / (C_DIM - 1);
    const int k = bk - b * (C_DIM - 1);
    const int tid = threadIdx.x;
    const int f4 = tid & (F4 - 1);       // 0..7
    const int t0 = tid >> 3;             // 0..31

    const float4* __restrict__ xk = (const float4*)x + (b * C_DIM + k) * T_DIM * F4;
    const float4* __restrict__ Mb = (const float4*)M + b * T_DIM * F4;

    float4 acc = make_float4(-INFINITY, -INFINITY, -INFINITY, -INFINITY);
    #pragma unroll 4
    for (int t = t0; t < T_DIM; t += 32) {
        float4 v = xk[t * F4 + f4];
        float4 m = Mb[t * F4 + f4];
        acc = fmax4(acc, fadd4(v, m));
    }

    __shared__ float4 red[256];
    red[tid] = acc;
    __syncthreads();
    #pragma unroll
    for (int s = 128; s >= F4; s >>= 1) {
        if (tid < s) red[tid] = fmax4(red[tid], red[tid + s]);
        __syncthreads();
    }
    if (tid < F4) {
        // out layout [B, 1, C-1, F] -> flat b*(C-1)*F + k*F + f
        ((float4*)out)[bk * F4 + tid] = red[tid];
    }
}

extern "C" void kernel_launch(void* const* d_in, const int* in_sizes, int n_in,
                              void* d_out, int out_size, void* d_ws, size_t ws_size,
                              hipStream_t stream) {
    const float* x = (const float*)d_in[0];
    float* out = (float*)d_out;
    float* M = (float*)d_ws;   // needs B*T*F*4 = 512 KiB of workspace

    // Pass 1: channel max -> M[b,t,f]
    channel_max_kernel<<<B_DIM * T_DIM, 256, 0, stream>>>(x, M);
    // Pass 2: out[b,k,f] = max_t (x[b,k,t,f] + M[b,t,f])
    pair_out_kernel<<<B_DIM * (C_DIM - 1), 256, 0, stream>>>(x, M, out);
}

// Round 2
// 127.094 us; speedup vs baseline: 1.0294x; 1.0294x over previous
//
#include <hip/hip_runtime.h>
#include <math.h>

// Problem constants (from reference): x is [B, C, T, F] float32.
// out[b,k,f] = max_{j,t} (x[b,j,t,f] + x[b,k,t,f])
//            = max_t ( x[b,k,t,f] + max_j x[b,j,t,f] )   (exact: fl(a+b) monotone in b)
#define B_DIM 8
#define C_DIM 160
#define T_DIM 512
#define F_DIM 32
#define F4 (F_DIM / 4)      // 8 float4 per (b,c,t) row
#define C1 (C_DIM - 1)      // 159 output channels

__device__ __forceinline__ float4 fmax4(float4 a, float4 b) {
    return make_float4(fmaxf(a.x, b.x), fmaxf(a.y, b.y),
                       fmaxf(a.z, b.z), fmaxf(a.w, b.w));
}
__device__ __forceinline__ float4 fadd4(float4 a, float4 b) {
    return make_float4(a.x + b.x, a.y + b.y, a.z + b.z, a.w + b.w);
}
__device__ __forceinline__ float4 shfl_xor4(float4 v, int m) {
    return make_float4(__shfl_xor(v.x, m), __shfl_xor(v.y, m),
                       __shfl_xor(v.z, m), __shfl_xor(v.w, m));
}

// Kernel 1: M[b,t,f] = max_c x[b,c,t,f]
// One block per (b, t-octet). tid -> (c-slice, t-local, f4); each wave-load is
// 1 KB fully contiguous (8 t-rows x 128 B). 40 loads/thread, 2-step LDS reduce.
__global__ __launch_bounds__(256)
void channel_max_kernel(const float* __restrict__ x, float* __restrict__ M) {
    const int bt8 = blockIdx.x;            // b*64 + t8
    const int b = bt8 >> 6;
    const int t_base = (bt8 & 63) << 3;    // t8 * 8
    const int tid = threadIdx.x;
    const int f4 = tid & 7;
    const int tl = (tid >> 3) & 7;
    const int cs = tid >> 6;               // 0..3 channel slice
    const int t = t_base + tl;

    const float4* __restrict__ x4 = (const float4*)x;
    const int base = (b * C_DIM * T_DIM + t) * F4 + f4;

    float4 acc = make_float4(-INFINITY, -INFINITY, -INFINITY, -INFINITY);
    #pragma unroll 8
    for (int i = 0; i < 40; ++i) {
        const int c = i * 4 + cs;          // 4 slices interleaved: c stays clustered
        acc = fmax4(acc, x4[base + c * (T_DIM * F4)]);
    }

    __shared__ float4 red[256];
    red[tid] = acc;
    __syncthreads();
    if (tid < 128) red[tid] = fmax4(red[tid], red[tid + 128]);
    __syncthreads();
    if (tid < 64) {
        const float4 v = fmax4(red[tid], red[tid + 64]);
        // M[(b*T + t_base + tl)*F4 + f4] with tid = tl*8+f4 -> 1 KB contiguous store
        ((float4*)M)[(b * T_DIM + t_base) * F4 + tid] = v;
    }
}

// Kernel 2: out[b,k,f] = max_t (x[b,k,t,f] + M[b,t,f])
// One wave per (b,k): idx = j*64+lane streams the 64 KB plane contiguously.
// 3-step shfl_xor reduce over the t-slice bits; no LDS, no barriers.
__global__ __launch_bounds__(64)
void pair_out_kernel(const float* __restrict__ x, const float* __restrict__ M,
                     float* __restrict__ out) {
    const int bk = blockIdx.x;             // b*159 + k
    const int b = bk / C1;
    const int k = bk - b * C1;
    const int lane = threadIdx.x;          // f4 = lane&7, t-slice = lane>>3

    const float4* __restrict__ xk = (const float4*)x + (b * C_DIM + k) * (T_DIM * F4);
    const float4* __restrict__ Mb = (const float4*)M + b * (T_DIM * F4);

    float4 acc = make_float4(-INFINITY, -INFINITY, -INFINITY, -INFINITY);
    #pragma unroll 8
    for (int j = 0; j < T_DIM * F4 / 64; ++j) {   // 64 iterations
        const int idx = j * 64 + lane;
        acc = fmax4(acc, fadd4(xk[idx], Mb[idx]));
    }

    acc = fmax4(acc, shfl_xor4(acc, 8));
    acc = fmax4(acc, shfl_xor4(acc, 16));
    acc = fmax4(acc, shfl_xor4(acc, 32));
    if (lane < 8) {
        // out layout [B,1,C-1,F] flat: bk*F + f; lane==f4 here
        ((float4*)out)[bk * F4 + lane] = acc;
    }
}

extern "C" void kernel_launch(void* const* d_in, const int* in_sizes, int n_in,
                              void* d_out, int out_size, void* d_ws, size_t ws_size,
                              hipStream_t stream) {
    const float* x = (const float*)d_in[0];
    float* out = (float*)d_out;
    float* M = (float*)d_ws;   // B*T*F*4 = 512 KiB scratch

    channel_max_kernel<<<B_DIM * (T_DIM / 8), 256, 0, stream>>>(x, M);      // 512 blocks
    pair_out_kernel<<<B_DIM * C1, 64, 0, stream>>>(x, M, out);              // 1272 waves
}